// Round 7
// baseline (650.627 us; speedup 1.0000x reference)
//
#include <hip/hip_runtime.h>

// 3-layer LSTM (B=8192, T=336, F=8, H=20) + FC(20->20 relu) + FC(20->1).
//
// Round 7: layer-SKEWED software pipeline on the R6 MFMA structure.
// Iteration i computes L0(t=i), L1(t=i-1), L2(t=i-2): the three layer blocks
// are mutually independent (all reads of old state precede all writes;
// per-wave DS ops are in-order), so the per-iteration critical path is ONE
// layer's MFMA->cell->LDS chain instead of three chained layers. Prologue
// (i=0,1) and epilogue (i=T,T+1) are peeled; hot loop is branch-free.
//  - Weights: 25 A-fragments + 15 bias C-fragments register-resident (R6).
//  - Occupancy is grid-limited (512 waves / 256 CU); VGPR growth is free.
//  - Per-layer bounce buffers (gbuf0/1/2) since bounces are now concurrent.
//  - LICM asm clobber kept (R4 fix; FETCH must stay ~45 MB).
//
// MFMA layouts (m89/m120-verified): A[m][k]: m=lane&15,k=(lane>>4)*8+j;
// B[k][n]: n=lane&15,k=(lane>>4)*8+j; D[m][n]: n=lane&15,m=(lane>>4)*4+reg.

#define T_LEN 336

typedef _Float16 f16;
typedef _Float16 f16x2 __attribute__((ext_vector_type(2)));
typedef _Float16 f16x4 __attribute__((ext_vector_type(4)));
typedef _Float16 f16x8 __attribute__((ext_vector_type(8)));
typedef float f32x4 __attribute__((ext_vector_type(4)));

#define MFMA(a, b, c) __builtin_amdgcn_mfma_f32_16x16x32_f16((a), (b), (c), 0, 0, 0)

__device__ __forceinline__ float sigm(float x) {
  return __builtin_amdgcn_rcpf(1.0f + __builtin_amdgcn_exp2f(-1.4426950408889634f * x));
}
__device__ __forceinline__ float tanh_fast(float x) {
  return 2.0f * __builtin_amdgcn_rcpf(1.0f + __builtin_amdgcn_exp2f(-2.8853900817779268f * x)) - 1.0f;
}

// gate-aligned tiles: lane(q,n) reg r = unit 4q+r, elem n — i,f,g,o in-lane
#define CELLS4(DI, DF, DG, DO, C0, C1, C2, C3, HV) {                                        \
  { float i_=sigm((DI)[0]), f_=sigm((DF)[0]), g_=tanh_fast((DG)[0]), o_=sigm((DO)[0]);      \
    C0 = f_*C0 + i_*g_; (HV)[0] = (f16)(o_*tanh_fast(C0)); }                                \
  { float i_=sigm((DI)[1]), f_=sigm((DF)[1]), g_=tanh_fast((DG)[1]), o_=sigm((DO)[1]);      \
    C1 = f_*C1 + i_*g_; (HV)[1] = (f16)(o_*tanh_fast(C1)); }                                \
  { float i_=sigm((DI)[2]), f_=sigm((DF)[2]), g_=tanh_fast((DG)[2]), o_=sigm((DO)[2]);      \
    C2 = f_*C2 + i_*g_; (HV)[2] = (f16)(o_*tanh_fast(C2)); }                                \
  { float i_=sigm((DI)[3]), f_=sigm((DF)[3]), g_=tanh_fast((DG)[3]), o_=sigm((DO)[3]);      \
    C3 = f_*C3 + i_*g_; (HV)[3] = (f16)(o_*tanh_fast(C3)); } }

// leftover tile (units 16..19 packed 4 rows/gate): bounce through GB
#define CELL_L(DL, CL, HOUT, GB) {                                                          \
  *(f32x4*)&GB[(q * 16 + n) * 4] = (DL);                                                    \
  float i_ = sigm(GB[n * 4 + q]);                                                           \
  float f_ = sigm(GB[(16 + n) * 4 + q]);                                                    \
  float g_ = tanh_fast(GB[(32 + n) * 4 + q]);                                               \
  float o_ = sigm(GB[(48 + n) * 4 + q]);                                                    \
  CL = f_*CL + i_*g_; HOUT = (f16)(o_*tanh_fast(CL)); }

// ---- per-iteration pieces (skewed pipeline) ----
// stage x(I) from prefetch regs, prefetch x(I+1)
#define STAGE_X(I) {                                                        \
  f16x2 xh_; xh_[0] = (f16)xr.x; xh_[1] = (f16)xr.y;                        \
  *(f16x2*)&zT0[n * 32 + 2 * q] = xh_;                                      \
  int tn_ = ((I) + 1 < T_LEN) ? (I) + 1 : T_LEN - 1;                        \
  xr = *(const float2*)(xp + (size_t)tn_ * 8); }

#define RD_B0 f16x8 b0 = *(const f16x8*)&zT0[n * 32 + q * 8];
#define RD_B1 f16x8 ba1 = *(const f16x8*)&zT1[n * 64 + q * 8];              \
              f16x8 bb1 = *(const f16x8*)&zT1[n * 64 + 32 + q * 8];
#define RD_B2 f16x8 ba2 = *(const f16x8*)&zT2[n * 64 + q * 8];              \
              f16x8 bb2 = *(const f16x8*)&zT2[n * 64 + 32 + q * 8];

#define DO_L0 {                                                             \
  f32x4 di = MFMA(A00, b0, Bi0), df = MFMA(A01, b0, Bf0),                   \
        dg = MFMA(A02, b0, Bg0), dn = MFMA(A03, b0, Bo0),                   \
        dl = MFMA(A04, b0, BL0);                                            \
  f16x4 hv; CELLS4(di, df, dg, dn, c00, c01, c02, c03, hv)                  \
  *(f16x4*)&zT0[n * 32 + 8 + q * 4] = hv;                                   \
  *(f16x4*)&zT1[n * 64 + q * 4]     = hv;                                   \
  f16 hl; CELL_L(dl, cL0, hl, gbuf0)                                        \
  zT0[n * 32 + 24 + q] = hl; zT1[n * 64 + 16 + q] = hl; }

#define DO_L1 {                                                             \
  f32x4 di = MFMA(W10b, bb1, MFMA(W10a, ba1, Bi1));                         \
  f32x4 df = MFMA(W11b, bb1, MFMA(W11a, ba1, Bf1));                         \
  f32x4 dg = MFMA(W12b, bb1, MFMA(W12a, ba1, Bg1));                         \
  f32x4 dn = MFMA(W13b, bb1, MFMA(W13a, ba1, Bo1));                         \
  f32x4 dl = MFMA(W14b, bb1, MFMA(W14a, ba1, BL1));                         \
  f16x4 hv; CELLS4(di, df, dg, dn, c10, c11, c12, c13, hv)                  \
  *(f16x4*)&zT1[n * 64 + 20 + q * 4] = hv;                                  \
  *(f16x4*)&zT2[n * 64 + q * 4]      = hv;                                  \
  f16 hl; CELL_L(dl, cL1, hl, gbuf1)                                        \
  zT1[n * 64 + 36 + q] = hl; zT2[n * 64 + 16 + q] = hl; }

#define DO_L2 {                                                             \
  f32x4 di = MFMA(W20b, bb2, MFMA(W20a, ba2, Bi2));                         \
  f32x4 df = MFMA(W21b, bb2, MFMA(W21a, ba2, Bf2));                         \
  f32x4 dg = MFMA(W22b, bb2, MFMA(W22a, ba2, Bg2));                         \
  f32x4 dn = MFMA(W23b, bb2, MFMA(W23a, ba2, Bo2));                         \
  f32x4 dl = MFMA(W24b, bb2, MFMA(W24a, ba2, BL2));                         \
  f16x4 hv; CELLS4(di, df, dg, dn, c20, c21, c22, c23, hv)                  \
  *(f16x4*)&zT2[n * 64 + 20 + q * 4] = hv;                                  \
  f16 hl; CELL_L(dl, cL2, hl, gbuf2)                                        \
  zT2[n * 64 + 36 + q] = hl; }

__global__ __launch_bounds__(64, 1) void lstm3_mfma_kernel(
    const float* __restrict__ x,
    const float* __restrict__ Wih0, const float* __restrict__ Whh0,
    const float* __restrict__ bih0, const float* __restrict__ bhh0,
    const float* __restrict__ Wih1, const float* __restrict__ Whh1,
    const float* __restrict__ bih1, const float* __restrict__ bhh1,
    const float* __restrict__ Wih2, const float* __restrict__ Whh2,
    const float* __restrict__ bih2, const float* __restrict__ bhh2,
    const float* __restrict__ fc1w, const float* __restrict__ fc1b,
    const float* __restrict__ fc2w, const float* __restrict__ fc2b,
    float* __restrict__ out)
{
  __shared__ __align__(16) f16 zT0[16 * 32];   // [elem][k]: x8|h0 20|pad4
  __shared__ __align__(16) f16 zT1[16 * 64];   // h0 20|h1 20|pad24
  __shared__ __align__(16) f16 zT2[16 * 64];   // h1 20|h2 20|pad24
  __shared__ __align__(16) float gbuf0[256], gbuf1[256], gbuf2[256];
  __shared__ __align__(16) float pbuf[16 * 4];

  const int lane = threadIdx.x;
  const int n = lane & 15;
  const int q = lane >> 4;

  // ---- zero z buffers (h(0)=c(0)=0; pads finite) ----
  {
    f16x8 zer;
#pragma unroll
    for (int j = 0; j < 8; ++j) zer[j] = (f16)0.f;
    ((f16x8*)zT0)[lane] = zer;
    ((f16x8*)zT1)[lane] = zer; ((f16x8*)zT1)[lane + 64] = zer;
    ((f16x8*)zT2)[lane] = zer; ((f16x8*)zT2)[lane + 64] = zer;
  }

  // ---- register-resident weight/bias fragments (as R6) ----
  auto rowmap = [](int T, int m) { return T < 4 ? T * 20 + m : (m >> 2) * 20 + 16 + (m & 3); };
  auto gA0 = [&](int T) {
    int row = rowmap(T, n);
    f16x8 r;
#pragma unroll
    for (int j = 0; j < 8; ++j) {
      int k = q * 8 + j;
      float v = (k < 8) ? Wih0[row * 8 + k] : (k < 28 ? Whh0[row * 20 + k - 8] : 0.f);
      r[j] = (f16)v;
    }
    return r;
  };
  auto gA = [&](const float* Wih, const float* Whh, int T, int c) {
    int row = rowmap(T, n);
    f16x8 r;
#pragma unroll
    for (int j = 0; j < 8; ++j) {
      int k = c * 32 + q * 8 + j;
      float v = (k < 20) ? Wih[row * 20 + k] : (k < 40 ? Whh[row * 20 + k - 20] : 0.f);
      r[j] = (f16)v;
    }
    return r;
  };
  auto gBias = [&](const float* bi, const float* bh, int T) {
    f32x4 r;
#pragma unroll
    for (int j = 0; j < 4; ++j) {
      int row = rowmap(T, q * 4 + j);
      r[j] = bi[row] + bh[row];
    }
    return r;
  };

  const f16x8 A00 = gA0(0), A01 = gA0(1), A02 = gA0(2), A03 = gA0(3), A04 = gA0(4);
  const f16x8 W10a = gA(Wih1, Whh1, 0, 0), W10b = gA(Wih1, Whh1, 0, 1);
  const f16x8 W11a = gA(Wih1, Whh1, 1, 0), W11b = gA(Wih1, Whh1, 1, 1);
  const f16x8 W12a = gA(Wih1, Whh1, 2, 0), W12b = gA(Wih1, Whh1, 2, 1);
  const f16x8 W13a = gA(Wih1, Whh1, 3, 0), W13b = gA(Wih1, Whh1, 3, 1);
  const f16x8 W14a = gA(Wih1, Whh1, 4, 0), W14b = gA(Wih1, Whh1, 4, 1);
  const f16x8 W20a = gA(Wih2, Whh2, 0, 0), W20b = gA(Wih2, Whh2, 0, 1);
  const f16x8 W21a = gA(Wih2, Whh2, 1, 0), W21b = gA(Wih2, Whh2, 1, 1);
  const f16x8 W22a = gA(Wih2, Whh2, 2, 0), W22b = gA(Wih2, Whh2, 2, 1);
  const f16x8 W23a = gA(Wih2, Whh2, 3, 0), W23b = gA(Wih2, Whh2, 3, 1);
  const f16x8 W24a = gA(Wih2, Whh2, 4, 0), W24b = gA(Wih2, Whh2, 4, 1);

  const f32x4 Bi0 = gBias(bih0, bhh0, 0), Bf0 = gBias(bih0, bhh0, 1),
              Bg0 = gBias(bih0, bhh0, 2), Bo0 = gBias(bih0, bhh0, 3), BL0 = gBias(bih0, bhh0, 4);
  const f32x4 Bi1 = gBias(bih1, bhh1, 0), Bf1 = gBias(bih1, bhh1, 1),
              Bg1 = gBias(bih1, bhh1, 2), Bo1 = gBias(bih1, bhh1, 3), BL1 = gBias(bih1, bhh1, 4);
  const f32x4 Bi2 = gBias(bih2, bhh2, 0), Bf2 = gBias(bih2, bhh2, 1),
              Bg2 = gBias(bih2, bhh2, 2), Bo2 = gBias(bih2, bhh2, 3), BL2 = gBias(bih2, bhh2, 4);

  float c00 = 0.f, c01 = 0.f, c02 = 0.f, c03 = 0.f, cL0 = 0.f;
  float c10 = 0.f, c11 = 0.f, c12 = 0.f, c13 = 0.f, cL1 = 0.f;
  float c20 = 0.f, c21 = 0.f, c22 = 0.f, c23 = 0.f, cL2 = 0.f;

  const float* xp = x + (size_t)(blockIdx.x * 16 + n) * (T_LEN * 8) + 2 * q;
  float2 xr = *(const float2*)(xp);   // x(0) preload

  // ---- prologue: i=0 (L0 only), i=1 (L0+L1) ----
  {
    asm volatile("" ::: "memory");
    STAGE_X(0)
    RD_B0
    DO_L0
  }
  {
    asm volatile("" ::: "memory");
    STAGE_X(1)
    RD_B0 RD_B1          // reads of old state BEFORE L0's writes
    DO_L0 DO_L1
  }

  // ---- main skewed loop: i = 2..T-1 -> L0(i), L1(i-1), L2(i-2) ----
#pragma unroll 1
  for (int i = 2; i < T_LEN; ++i) {
    asm volatile("" ::: "memory");
    STAGE_X(i)
    RD_B0 RD_B1 RD_B2    // all reads precede all writes (DS in-order)
    DO_L0 DO_L1 DO_L2
  }

  // ---- epilogue: i=T (L1+L2), i=T+1 (L2) ----
  {
    asm volatile("" ::: "memory");
    RD_B1 RD_B2
    DO_L1 DO_L2
  }
  {
    asm volatile("" ::: "memory");
    RD_B2
    DO_L2
  }

  // ---- FC head: h2(T-1) = zT2[n][20..39] ----
  {
    f16x4 hv0 = *(const f16x4*)&zT2[n * 64 + 20];
    f16x4 hv1 = *(const f16x4*)&zT2[n * 64 + 24];
    f16x4 hv2 = *(const f16x4*)&zT2[n * 64 + 28];
    f16x4 hv3 = *(const f16x4*)&zT2[n * 64 + 32];
    f16x4 hv4 = *(const f16x4*)&zT2[n * 64 + 36];
    float p = 0.f;
#pragma unroll
    for (int i = 0; i < 5; ++i) {
      int d = q * 5 + i;
      const float* wr = fc1w + d * 20;
      float s = fc1b[d]
        + wr[0]  * (float)hv0[0] + wr[1]  * (float)hv0[1] + wr[2]  * (float)hv0[2] + wr[3]  * (float)hv0[3]
        + wr[4]  * (float)hv1[0] + wr[5]  * (float)hv1[1] + wr[6]  * (float)hv1[2] + wr[7]  * (float)hv1[3]
        + wr[8]  * (float)hv2[0] + wr[9]  * (float)hv2[1] + wr[10] * (float)hv2[2] + wr[11] * (float)hv2[3]
        + wr[12] * (float)hv3[0] + wr[13] * (float)hv3[1] + wr[14] * (float)hv3[2] + wr[15] * (float)hv3[3]
        + wr[16] * (float)hv4[0] + wr[17] * (float)hv4[1] + wr[18] * (float)hv4[2] + wr[19] * (float)hv4[3];
      p += fc2w[d] * fmaxf(s, 0.f);
    }
    pbuf[n * 4 + q] = p;
  }
  if (q == 0) {
    f32x4 pv = *(const f32x4*)&pbuf[n * 4];
    out[blockIdx.x * 16 + n] = pv[0] + pv[1] + pv[2] + pv[3] + fc2b[0];
  }
}

extern "C" void kernel_launch(void* const* d_in, const int* in_sizes, int n_in,
                              void* d_out, int out_size, void* d_ws, size_t ws_size,
                              hipStream_t stream) {
  const float* x    = (const float*)d_in[0];
  const float* Wih0 = (const float*)d_in[1];
  const float* Whh0 = (const float*)d_in[2];
  const float* bih0 = (const float*)d_in[3];
  const float* bhh0 = (const float*)d_in[4];
  const float* Wih1 = (const float*)d_in[5];
  const float* Whh1 = (const float*)d_in[6];
  const float* bih1 = (const float*)d_in[7];
  const float* bhh1 = (const float*)d_in[8];
  const float* Wih2 = (const float*)d_in[9];
  const float* Whh2 = (const float*)d_in[10];
  const float* bih2 = (const float*)d_in[11];
  const float* bhh2 = (const float*)d_in[12];
  const float* fc1w = (const float*)d_in[13];
  const float* fc1b = (const float*)d_in[14];
  const float* fc2w = (const float*)d_in[15];
  const float* fc2b = (const float*)d_in[16];
  float* out = (float*)d_out;

  hipLaunchKernelGGL(lstm3_mfma_kernel, dim3(8192 / 16), dim3(64), 0, stream,
                     x, Wih0, Whh0, bih0, bhh0,
                     Wih1, Whh1, bih1, bhh1,
                     Wih2, Whh2, bih2, bhh2,
                     fc1w, fc1b, fc2w, fc2b, out);
}

// Round 8
// 483.854 us; speedup vs baseline: 1.3447x; 1.3447x over previous
//
#include <hip/hip_runtime.h>

// 3-layer LSTM (B=8192, T=336, F=8, H=20) + FC(20->20 relu) + FC(20->1).
//
// Round 8: WAVE-SPECIALIZED layer pipeline. R7's skew made L0(i), L1(i-1),
// L2(i-2) independent but one wave still issued all three (2 waves/CU ->
// nothing hides the ~2700cyc/iter of latency). Now block = 3 waves; wave w
// owns layer w (its 10 A-frags + biases + c in registers, ~40 VGPR), and one
// __syncthreads() per iteration publishes h across waves:
//   iter i: w0 computes L0(t=i), w1 L1(t=i-1), w2 L2(t=i-2).
// h handoff via PARITY double-buffered z-vectors (zT1/zT2[i&1]) so reads of
// parity (i-1)&1 never collide with same-iteration writes to parity i&1;
// the barrier orders cross-iteration reuse. 512 blocks x 192 thr = 1536
// waves = 6/CU (3x R7), ~2 blocks/CU overlap each other's barrier stalls.
//  - zT0 (x|h0) is wave0-private: in-order DS, single-buffered (R6 proven).
//  - Same MFMA tile scheme as R6/R7 (gate-aligned tiles, leftover bounce).
//  - LICM asm clobber kept (R4): FETCH must stay ~45 MB.
//
// MFMA layouts (m89/m120-verified): A[m][k]: m=lane&15,k=(lane>>4)*8+j;
// B[k][n]: n=lane&15,k=(lane>>4)*8+j; D[m][n]: n=lane&15,m=(lane>>4)*4+reg.

#define T_LEN 336

typedef _Float16 f16;
typedef _Float16 f16x2 __attribute__((ext_vector_type(2)));
typedef _Float16 f16x4 __attribute__((ext_vector_type(4)));
typedef _Float16 f16x8 __attribute__((ext_vector_type(8)));
typedef float f32x4 __attribute__((ext_vector_type(4)));

#define MFMA(a, b, c) __builtin_amdgcn_mfma_f32_16x16x32_f16((a), (b), (c), 0, 0, 0)

__device__ __forceinline__ float sigm(float x) {
  return __builtin_amdgcn_rcpf(1.0f + __builtin_amdgcn_exp2f(-1.4426950408889634f * x));
}
__device__ __forceinline__ float tanh_fast(float x) {
  return 2.0f * __builtin_amdgcn_rcpf(1.0f + __builtin_amdgcn_exp2f(-2.8853900817779268f * x)) - 1.0f;
}

// gate-aligned tiles: lane(q,n) reg r = unit 4q+r, elem n — i,f,g,o in-lane
#define CELLS4(DI, DF, DG, DO, HV) {                                                        \
  { float i_=sigm((DI)[0]), f_=sigm((DF)[0]), g_=tanh_fast((DG)[0]), o_=sigm((DO)[0]);      \
    c0 = f_*c0 + i_*g_; (HV)[0] = (f16)(o_*tanh_fast(c0)); }                                \
  { float i_=sigm((DI)[1]), f_=sigm((DF)[1]), g_=tanh_fast((DG)[1]), o_=sigm((DO)[1]);      \
    c1 = f_*c1 + i_*g_; (HV)[1] = (f16)(o_*tanh_fast(c1)); }                                \
  { float i_=sigm((DI)[2]), f_=sigm((DF)[2]), g_=tanh_fast((DG)[2]), o_=sigm((DO)[2]);      \
    c2 = f_*c2 + i_*g_; (HV)[2] = (f16)(o_*tanh_fast(c2)); }                                \
  { float i_=sigm((DI)[3]), f_=sigm((DF)[3]), g_=tanh_fast((DG)[3]), o_=sigm((DO)[3]);      \
    c3 = f_*c3 + i_*g_; (HV)[3] = (f16)(o_*tanh_fast(c3)); } }

// leftover tile (units 16..19 packed 4 rows/gate): bounce through GB (wave-private)
#define CELL_L(DL, HOUT, GB) {                                                              \
  *(f32x4*)&GB[(q * 16 + n) * 4] = (DL);                                                    \
  float i_ = sigm(GB[n * 4 + q]);                                                           \
  float f_ = sigm(GB[(16 + n) * 4 + q]);                                                    \
  float g_ = tanh_fast(GB[(32 + n) * 4 + q]);                                               \
  float o_ = sigm(GB[(48 + n) * 4 + q]);                                                    \
  cL = f_*cL + i_*g_; HOUT = (f16)(o_*tanh_fast(cL)); }

__global__ __launch_bounds__(192, 2) void lstm3_ws_kernel(
    const float* __restrict__ x,
    const float* __restrict__ Wih0, const float* __restrict__ Whh0,
    const float* __restrict__ bih0, const float* __restrict__ bhh0,
    const float* __restrict__ Wih1, const float* __restrict__ Whh1,
    const float* __restrict__ bih1, const float* __restrict__ bhh1,
    const float* __restrict__ Wih2, const float* __restrict__ Whh2,
    const float* __restrict__ bih2, const float* __restrict__ bhh2,
    const float* __restrict__ fc1w, const float* __restrict__ fc1b,
    const float* __restrict__ fc2w, const float* __restrict__ fc2b,
    float* __restrict__ out)
{
  __shared__ __align__(16) f16 zT0[16 * 32];        // wave0-private: x8|h0 20|pad4
  __shared__ __align__(16) f16 zT1[2][16 * 64];     // parity: h0 20|h1 20|pad24
  __shared__ __align__(16) f16 zT2[2][16 * 64];     // parity: h1 20|h2 20|pad24
  __shared__ __align__(16) float gbuf[3][256];      // per-wave leftover bounce
  __shared__ __align__(16) float pbuf[64];          // fc2 partials

  const int tid  = threadIdx.x;
  const int w    = tid >> 6;        // wave id = layer id
  const int lane = tid & 63;
  const int n = lane & 15;          // elem (M/N index)
  const int q = lane >> 4;          // quad

  // ---- zero z buffers (h(.)=0 initial, pads 0) ----
  {
    f16x8 zer;
#pragma unroll
    for (int j = 0; j < 8; ++j) zer[j] = (f16)0.f;
    for (int i = tid; i < 64; i += 192)  ((f16x8*)zT0)[i] = zer;
    for (int i = tid; i < 256; i += 192) ((f16x8*)&zT1[0][0])[i] = zer;
    for (int i = tid; i < 256; i += 192) ((f16x8*)&zT2[0][0])[i] = zer;
  }
  __syncthreads();

  // ---- per-wave register-resident fragments ----
  auto rowmap = [](int T, int m) { return T < 4 ? T * 20 + m : (m >> 2) * 20 + 16 + (m & 3); };

  f16x8 Fa0{}, Fa1{}, Fa2{}, Fa3{}, Fa4{};   // chunk 0 (or full K=32 for L0)
  f16x8 Fb0{}, Fb1{}, Fb2{}, Fb3{}, Fb4{};   // chunk 1 (unused by wave0)
  f32x4 Bi{}, Bf{}, Bg{}, Bo{}, BL{};
  float c0 = 0.f, c1 = 0.f, c2 = 0.f, c3 = 0.f, cL = 0.f;

  if (w == 0) {
    auto gA0 = [&](int T) {
      int row = rowmap(T, n);
      f16x8 r;
#pragma unroll
      for (int j = 0; j < 8; ++j) {
        int k = q * 8 + j;
        float v = (k < 8) ? Wih0[row * 8 + k] : (k < 28 ? Whh0[row * 20 + k - 8] : 0.f);
        r[j] = (f16)v;
      }
      return r;
    };
    Fa0 = gA0(0); Fa1 = gA0(1); Fa2 = gA0(2); Fa3 = gA0(3); Fa4 = gA0(4);
    auto gB = [&](int T) {
      f32x4 r;
#pragma unroll
      for (int j = 0; j < 4; ++j) { int row = rowmap(T, q * 4 + j); r[j] = bih0[row] + bhh0[row]; }
      return r;
    };
    Bi = gB(0); Bf = gB(1); Bg = gB(2); Bo = gB(3); BL = gB(4);
  } else {
    const float* Wi = (w == 1) ? Wih1 : Wih2;
    const float* Wh = (w == 1) ? Whh1 : Whh2;
    const float* bi = (w == 1) ? bih1 : bih2;
    const float* bh = (w == 1) ? bhh1 : bhh2;
    auto gA = [&](int T, int c) {
      int row = rowmap(T, n);
      f16x8 r;
#pragma unroll
      for (int j = 0; j < 8; ++j) {
        int k = c * 32 + q * 8 + j;
        float v = (k < 20) ? Wi[row * 20 + k] : (k < 40 ? Wh[row * 20 + k - 20] : 0.f);
        r[j] = (f16)v;
      }
      return r;
    };
    Fa0 = gA(0, 0); Fb0 = gA(0, 1);
    Fa1 = gA(1, 0); Fb1 = gA(1, 1);
    Fa2 = gA(2, 0); Fb2 = gA(2, 1);
    Fa3 = gA(3, 0); Fb3 = gA(3, 1);
    Fa4 = gA(4, 0); Fb4 = gA(4, 1);
    auto gB = [&](int T) {
      f32x4 r;
#pragma unroll
      for (int j = 0; j < 4; ++j) { int row = rowmap(T, q * 4 + j); r[j] = bi[row] + bh[row]; }
      return r;
    };
    Bi = gB(0); Bf = gB(1); Bg = gB(2); Bo = gB(3); BL = gB(4);
  }

  // x prefetch (wave0 only; harmless for others)
  const float* xp = x + (size_t)(blockIdx.x * 16 + n) * (T_LEN * 8) + 2 * q;
  float2 xr = (w == 0) ? *(const float2*)(xp) : float2{0.f, 0.f};

  // ---- skewed, wave-specialized main loop ----
#pragma unroll 1
  for (int i = 0; i <= T_LEN + 1; ++i) {
    asm volatile("" ::: "memory");   // pin LDS loads in-loop (R4 fix)
    if (w == 0) {
      if (i < T_LEN) {
        // stage x(i), prefetch x(i+1)
        f16x2 xh; xh[0] = (f16)xr.x; xh[1] = (f16)xr.y;
        *(f16x2*)&zT0[n * 32 + 2 * q] = xh;
        int tn = (i + 1 < T_LEN) ? i + 1 : T_LEN - 1;
        xr = *(const float2*)(xp + (size_t)tn * 8);
        // L0(t=i)
        f16x8 b0 = *(const f16x8*)&zT0[n * 32 + q * 8];
        f32x4 di = MFMA(Fa0, b0, Bi), df = MFMA(Fa1, b0, Bf),
              dg = MFMA(Fa2, b0, Bg), dn = MFMA(Fa3, b0, Bo),
              dl = MFMA(Fa4, b0, BL);
        f16x4 hv; CELLS4(di, df, dg, dn, hv)
        f16* d1 = &zT1[i & 1][0];
        *(f16x4*)&zT0[n * 32 + 8 + q * 4] = hv;      // self (in-order)
        *(f16x4*)&d1[n * 64 + q * 4] = hv;           // publish h0(i)
        f16 hl; CELL_L(dl, hl, gbuf[0])
        zT0[n * 32 + 24 + q] = hl;
        d1[n * 64 + 16 + q] = hl;
      }
    } else if (w == 1) {
      if (i >= 1 && i <= T_LEN) {
        // L1(t=i-1): reads h0(i-1), h1(i-2) from parity (i-1)&1
        const f16* src = &zT1[(i - 1) & 1][0];
        f16x8 ba = *(const f16x8*)&src[n * 64 + q * 8];
        f16x8 bb = *(const f16x8*)&src[n * 64 + 32 + q * 8];
        f32x4 di = MFMA(Fb0, bb, MFMA(Fa0, ba, Bi));
        f32x4 df = MFMA(Fb1, bb, MFMA(Fa1, ba, Bf));
        f32x4 dg = MFMA(Fb2, bb, MFMA(Fa2, ba, Bg));
        f32x4 dn = MFMA(Fb3, bb, MFMA(Fa3, ba, Bo));
        f32x4 dl = MFMA(Fb4, bb, MFMA(Fa4, ba, BL));
        f16x4 hv; CELLS4(di, df, dg, dn, hv)
        f16* d1 = &zT1[i & 1][0];
        f16* d2 = &zT2[i & 1][0];
        *(f16x4*)&d1[n * 64 + 20 + q * 4] = hv;      // self h1(i-1)
        *(f16x4*)&d2[n * 64 + q * 4] = hv;           // publish to L2
        f16 hl; CELL_L(dl, hl, gbuf[1])
        d1[n * 64 + 36 + q] = hl;
        d2[n * 64 + 16 + q] = hl;
      }
    } else {
      if (i >= 2) {
        // L2(t=i-2): reads h1(i-2), h2(i-3) from parity (i-1)&1
        const f16* src = &zT2[(i - 1) & 1][0];
        f16x8 ba = *(const f16x8*)&src[n * 64 + q * 8];
        f16x8 bb = *(const f16x8*)&src[n * 64 + 32 + q * 8];
        f32x4 di = MFMA(Fb0, bb, MFMA(Fa0, ba, Bi));
        f32x4 df = MFMA(Fb1, bb, MFMA(Fa1, ba, Bf));
        f32x4 dg = MFMA(Fb2, bb, MFMA(Fa2, ba, Bg));
        f32x4 dn = MFMA(Fb3, bb, MFMA(Fa3, ba, Bo));
        f32x4 dl = MFMA(Fb4, bb, MFMA(Fa4, ba, BL));
        f16x4 hv; CELLS4(di, df, dg, dn, hv)
        f16* d2 = &zT2[i & 1][0];
        *(f16x4*)&d2[n * 64 + 20 + q * 4] = hv;      // self h2(i-2)
        f16 hl; CELL_L(dl, hl, gbuf[2])
        d2[n * 64 + 36 + q] = hl;
      }
    }
    __syncthreads();   // one barrier per pipeline step, single call site
  }

  // ---- FC head (wave2; h2(T-1) is in zT2[(T+1)&1], written by wave2) ----
  if (w == 2) {
    const f16* hb = &zT2[(T_LEN + 1) & 1][0];
    f16x4 hv0 = *(const f16x4*)&hb[n * 64 + 20];
    f16x4 hv1 = *(const f16x4*)&hb[n * 64 + 24];
    f16x4 hv2 = *(const f16x4*)&hb[n * 64 + 28];
    f16x4 hv3 = *(const f16x4*)&hb[n * 64 + 32];
    f16x4 hv4 = *(const f16x4*)&hb[n * 64 + 36];
    float p = 0.f;
#pragma unroll
    for (int i = 0; i < 5; ++i) {
      int d = q * 5 + i;
      const float* wr = fc1w + d * 20;
      float s = fc1b[d]
        + wr[0]  * (float)hv0[0] + wr[1]  * (float)hv0[1] + wr[2]  * (float)hv0[2] + wr[3]  * (float)hv0[3]
        + wr[4]  * (float)hv1[0] + wr[5]  * (float)hv1[1] + wr[6]  * (float)hv1[2] + wr[7]  * (float)hv1[3]
        + wr[8]  * (float)hv2[0] + wr[9]  * (float)hv2[1] + wr[10] * (float)hv2[2] + wr[11] * (float)hv2[3]
        + wr[12] * (float)hv3[0] + wr[13] * (float)hv3[1] + wr[14] * (float)hv3[2] + wr[15] * (float)hv3[3]
        + wr[16] * (float)hv4[0] + wr[17] * (float)hv4[1] + wr[18] * (float)hv4[2] + wr[19] * (float)hv4[3];
      p += fc2w[d] * fmaxf(s, 0.f);
    }
    pbuf[n * 4 + q] = p;            // wave-internal, in-order
    if (q == 0) {
      f32x4 pv = *(const f32x4*)&pbuf[n * 4];
      out[blockIdx.x * 16 + n] = pv[0] + pv[1] + pv[2] + pv[3] + fc2b[0];
    }
  }
}

extern "C" void kernel_launch(void* const* d_in, const int* in_sizes, int n_in,
                              void* d_out, int out_size, void* d_ws, size_t ws_size,
                              hipStream_t stream) {
  const float* x    = (const float*)d_in[0];
  const float* Wih0 = (const float*)d_in[1];
  const float* Whh0 = (const float*)d_in[2];
  const float* bih0 = (const float*)d_in[3];
  const float* bhh0 = (const float*)d_in[4];
  const float* Wih1 = (const float*)d_in[5];
  const float* Whh1 = (const float*)d_in[6];
  const float* bih1 = (const float*)d_in[7];
  const float* bhh1 = (const float*)d_in[8];
  const float* Wih2 = (const float*)d_in[9];
  const float* Whh2 = (const float*)d_in[10];
  const float* bih2 = (const float*)d_in[11];
  const float* bhh2 = (const float*)d_in[12];
  const float* fc1w = (const float*)d_in[13];
  const float* fc1b = (const float*)d_in[14];
  const float* fc2w = (const float*)d_in[15];
  const float* fc2b = (const float*)d_in[16];
  float* out = (float*)d_out;

  hipLaunchKernelGGL(lstm3_ws_kernel, dim3(8192 / 16), dim3(192), 0, stream,
                     x, Wih0, Whh0, bih0, bhh0,
                     Wih1, Whh1, bih1, bhh1,
                     Wih2, Whh2, bih2, bhh2,
                     fc1w, fc1b, fc2w, fc2b, out);
}